// Round 1
// baseline (51.395 us; speedup 1.0000x reference)
//
#include <hip/hip_runtime.h>

// Problem constants (from reference)
#define NSPLIT  100
#define MTREE   20      // trees per split
#define MAXLEAF 64
#define EMB     32      // embedding size
#define BATCH   4096
#define NTREES  2000    // NSPLIT * MTREE

#define BPB     32      // batches per block
#define CHUNKS  (BATCH / BPB)   // 128 chunks per split

// Block: 256 threads = 32 (batch) groups x 8 lanes, each lane owns a float4
// slice of the 32-float embedding row.
// Grid:  NSPLIT * CHUNKS blocks; blockIdx = s*CHUNKS + chunk so co-resident
// blocks share few splits -> per-XCD L2 holds the 160KB tables being gathered.
__global__ __launch_bounds__(256) void leaf2emb_kernel(
    const int* __restrict__ leaves,     // [BATCH, NTREES]
    const float* __restrict__ embed,    // [NSPLIT, MTREE*MAXLEAF, EMB]
    float* __restrict__ out)            // [BATCH, NSPLIT*EMB]
{
    const int s     = blockIdx.x >> 7;        // / CHUNKS
    const int chunk = blockIdx.x & (CHUNKS - 1);
    const int tid   = threadIdx.x;
    const int e4    = tid & 7;                // which float4 of the row
    const int p     = tid >> 3;               // which batch in this block
    const int b     = chunk * BPB + p;

    // Load the 20 leaf ids for (b, s): 5 x int4, 16B-aligned (2000,20 % 4 == 0)
    const int* lv = leaves + b * NTREES + s * MTREE;
    const int4 l0 = *(const int4*)(lv + 0);
    const int4 l1 = *(const int4*)(lv + 4);
    const int4 l2 = *(const int4*)(lv + 8);
    const int4 l3 = *(const int4*)(lv + 12);
    const int4 l4 = *(const int4*)(lv + 16);

    // Base of this split's table, offset to this lane's float4 column
    const float* eb = embed + (size_t)s * (MTREE * MAXLEAF * EMB) + e4 * 4;

    float4 acc = make_float4(0.f, 0.f, 0.f, 0.f);
#define ACC(T, LEAF)                                                   \
    {                                                                  \
        const float4 v = *(const float4*)(eb + ((T)*MAXLEAF + (LEAF)) * EMB); \
        acc.x += v.x; acc.y += v.y; acc.z += v.z; acc.w += v.w;        \
    }
    ACC(0,  l0.x) ACC(1,  l0.y) ACC(2,  l0.z) ACC(3,  l0.w)
    ACC(4,  l1.x) ACC(5,  l1.y) ACC(6,  l1.z) ACC(7,  l1.w)
    ACC(8,  l2.x) ACC(9,  l2.y) ACC(10, l2.z) ACC(11, l2.w)
    ACC(12, l3.x) ACC(13, l3.y) ACC(14, l3.z) ACC(15, l3.w)
    ACC(16, l4.x) ACC(17, l4.y) ACC(18, l4.z) ACC(19, l4.w)
#undef ACC

    // out[b, s*EMB + e4*4 ..] — 8 lanes x 16B = one contiguous 128B line per b
    *(float4*)(out + (size_t)b * (NSPLIT * EMB) + s * EMB + e4 * 4) = acc;
}

extern "C" void kernel_launch(void* const* d_in, const int* in_sizes, int n_in,
                              void* d_out, int out_size, void* d_ws, size_t ws_size,
                              hipStream_t stream) {
    const int* leaves   = (const int*)d_in[0];
    const float* embed  = (const float*)d_in[1];
    float* out          = (float*)d_out;

    dim3 grid(NSPLIT * CHUNKS);
    dim3 block(256);
    leaf2emb_kernel<<<grid, block, 0, stream>>>(leaves, embed, out);
}